// Round 3
// baseline (485.196 us; speedup 1.0000x reference)
//
#include <hip/hip_runtime.h>
#include <math.h>

// Problem constants (fixed by reference setup_inputs)
#define B   8
#define C   64
#define HH  192
#define WWD 192
#define P   (HH*WWD)     // 36864
#define NC  2
#define NS  8
#define PP  (194*194)    // padded space map (1-px zero halo), 37636

// Workspace layout (float offsets)
#define OFF_SPACE 0                    // 128 maps * PP = 4817408 (zero-padded)
#define OFF_SPART 4817408              // 128*144 per-block S partials
#define OFF_R     4835840              // 8*16*64*9 = 73728 correlations (zeroed; k_R2 atomically accumulates)
#define OFF_TOK2  4909568              // 8*2*64 = 1024 (atomic accumulated, needs zero)
#define OFF_U     4910592              // 8*64*2*9 = 9216 collapsed conv weights
#define OFF_STP   4919808              // 2*64*288 BN partial sums
#define OFF_SCALE 4956672              // 64
#define OFF_SHIFT 4956736              // 64
#define WS_FLOATS 4956800              // ~19.8 MB total

__device__ __forceinline__ float sigm(float x) { return 1.0f / (1.0f + expf(-x)); }

// K1: space maps (sigmoid + 1->7 ch 3x3 conv + sigmoid) into zero-padded layout,
// plus per-(map,ch) per-block partial sums (NO global atomics).
__global__ void k_space(const float* __restrict__ cs, const float* __restrict__ Wc,
                        float* __restrict__ spp, float* __restrict__ Spart) {
    int m = blockIdx.y;                       // m = b*2 + c
    int bx = blockIdx.x;
    int p = bx * 256 + threadIdx.x;           // 144*256 == P exactly
    int h = p / WWD, w = p - (p / WWD) * WWD;
    float cp[9];
    #pragma unroll
    for (int ky = 0; ky < 3; ky++)
        #pragma unroll
        for (int kx = 0; kx < 3; kx++) {
            int hh = h + ky - 1, ww = w + kx - 1;
            float v = 0.f;  // zero-pad AFTER sigmoid (conv pads class_prob with 0)
            if ((unsigned)hh < HH && (unsigned)ww < WWD)
                v = sigm(cs[m * P + hh * WWD + ww]);
            cp[ky * 3 + kx] = v;
        }
    float ch[8];
    ch[0] = cp[4];
    #pragma unroll
    for (int j = 0; j < 7; j++) {
        float a = 0.f;
        #pragma unroll
        for (int k = 0; k < 9; k++) a += Wc[j * 9 + k] * cp[k];
        ch[j + 1] = sigm(a);
    }
    #pragma unroll
    for (int q = 0; q < 8; q++)
        spp[(m * 8 + q) * PP + (h + 1) * 194 + (w + 1)] = ch[q];
    // per-wave shfl reduce -> LDS -> per-block partial (no atomics)
    __shared__ float red[4][8];
    int lane = threadIdx.x & 63, wave = threadIdx.x >> 6;
    #pragma unroll
    for (int q = 0; q < 8; q++) {
        float v = ch[q];
        for (int off = 32; off > 0; off >>= 1) v += __shfl_down(v, off);
        if (lane == 0) red[wave][q] = v;
    }
    __syncthreads();
    if (threadIdx.x < 8) {
        int q = threadIdx.x;
        Spart[(m * 8 + q) * 144 + bx] = red[0][q] + red[1][q] + red[2][q] + red[3][q];
    }
}

// K2: register-tiled correlation, one space map x 8 x-channels per block (84-reg core).
// REVERTED from 2-map (R2 spilled at the 128-reg band: WRITE_SIZE +44MB, VALUBusy -10).
// NEW: explicit one-iteration-ahead double buffer (xn) for the 8 long-latency x loads
// (L3-served, ~600cy) so they fly under the 576-cycle FMA phase; K-split x4 (9 iters
// per block, 4096 blocks) for fill/tail. Both buffers live through FMAs: ~150-165
// VGPR -> fits the (256,3) 170-reg band without spill.
// Partials accumulated into R via atomicAdd (R pre-zeroed by memset).
__launch_bounds__(256, 3)
__global__ void k_R2(const float* __restrict__ x, const float* __restrict__ spp,
                     float* __restrict__ R) {
    int ig = blockIdx.x;    // 0..7 : i = ig*8 + il
    int yz = blockIdx.y;    // 0..63 : sc = yz&15, quarter = yz>>4
    int b  = blockIdx.z;
    int sc = yz & 15;
    int q  = yz >> 4;
    int s = sc >> 1, c = sc & 1;
    const float* xb = x + (b * C + ig * 8) * P;
    const float* sp = spp + ((b * NC + c) * NS + s) * PP;

    float acc[8][9];
    #pragma unroll
    for (int i = 0; i < 8; i++)
        #pragma unroll
        for (int t = 0; t < 9; t++) acc[i][t] = 0.f;

    int p0 = q * 9216 + threadIdx.x * 4;      // this block's quarter: 9 iters x 1024 px
    float4 xv[8], xn[8];
    #pragma unroll
    for (int i = 0; i < 8; i++) xv[i] = *(const float4*)(xb + i * P + p0);

    for (int it = 0; it < 9; it++) {
        int pc = p0 + it * 1024;
        int h = pc / WWD, w0 = pc - (pc / WWD) * WWD;
        if (it < 8) {                          // prefetch next iteration's x
            int pn = pc + 1024;
            #pragma unroll
            for (int i = 0; i < 8; i++) xn[i] = *(const float4*)(xb + i * P + pn);
        }
        float g[3][6];
        #pragma unroll
        for (int ty = 0; ty < 3; ty++) {
            const float* rp = sp + (h + 2 - ty) * 194 + w0;
            #pragma unroll
            for (int cc = 0; cc < 6; cc++) g[ty][cc] = rp[cc];
        }
        #pragma unroll
        for (int ty = 0; ty < 3; ty++)
            #pragma unroll
            for (int tx = 0; tx < 3; tx++) {
                float g0 = g[ty][2 - tx], g1 = g[ty][3 - tx];
                float g2 = g[ty][4 - tx], g3 = g[ty][5 - tx];
                #pragma unroll
                for (int i = 0; i < 8; i++) {
                    float a = acc[i][ty * 3 + tx];
                    a += xv[i].x * g0; a += xv[i].y * g1;
                    a += xv[i].z * g2; a += xv[i].w * g3;
                    acc[i][ty * 3 + tx] = a;
                }
            }
        #pragma unroll
        for (int i = 0; i < 8; i++) xv[i] = xn[i];
    }

    __shared__ float red[4][72];
    int lane = threadIdx.x & 63, wave = threadIdx.x >> 6;
    #pragma unroll
    for (int i = 0; i < 8; i++)
        #pragma unroll
        for (int t = 0; t < 9; t++) {
            float v = acc[i][t];
            for (int off = 32; off > 0; off >>= 1) v += __shfl_down(v, off);
            if (lane == 0) red[wave][i * 9 + t] = v;
        }
    __syncthreads();
    if (threadIdx.x < 72) {
        int i = threadIdx.x / 9, t = threadIdx.x - (threadIdx.x / 9) * 9;
        float v = red[0][threadIdx.x] + red[1][threadIdx.x] +
                  red[2][threadIdx.x] + red[3][threadIdx.x];
        atomicAdd(&R[((b * 16 + sc) * 64 + (ig * 8 + i)) * 9 + t], v);
    }
}

// K3: tok2[b,c,d] = sum_s Wcs[s]/S[b,c,s] * sum_{i,k} Wxs[s*64+d,i,k] * R[b,s,c,i,k]
// S reduced in-block from Spart (144 partials).
__global__ void k_tok2(const float* __restrict__ Wxs, const float* __restrict__ Wcs,
                       const float* __restrict__ R, const float* __restrict__ Spart,
                       float* __restrict__ tok2) {
    int bc = blockIdx.x, s = blockIdx.y;
    int d = threadIdx.x;
    const float* spp = Spart + (bc * 8 + s) * 144;
    float sv = 0.f;
    for (int k = d; k < 144; k += 64) sv += spp[k];
    #pragma unroll
    for (int msk = 32; msk >= 1; msk >>= 1) sv += __shfl_xor(sv, msk);

    const float* Rp = R + ((bc & 1) + ((bc >> 1) * 16 + s * 2)) * 64 * 9;
    const float* Wp = Wxs + (s * C + d) * (C * 9);
    float a = 0.f;
    for (int t = 0; t < C * 9; t++) a += Wp[t] * Rp[t];
    float val = a * Wcs[s] / sv;
    atomicAdd(&tok2[bc * C + d], val);   // 8K atomics over 1024 addrs — negligible
}

// K4: collapse conv weights against tok2:  U[b][oc][m][t] = sum_ci Ws[oc,ci,t] * tok2[b,m,ci]
__global__ void k_U(const float* __restrict__ Ws, const float* __restrict__ tok2,
                    float* __restrict__ U) {
    int b = blockIdx.x, m = blockIdx.y, oc = threadIdx.x;
    const float* tp = tok2 + (b * NC + m) * C;
    float u[9];
    #pragma unroll
    for (int t = 0; t < 9; t++) u[t] = 0.f;
    for (int ci = 0; ci < C; ci++) {
        float tv = tp[ci];
        const float* wp = Ws + (oc * C + ci) * 9;
        #pragma unroll
        for (int t = 0; t < 9; t++) u[t] += wp[t] * tv;
    }
    float* up = U + ((b * C + oc) * 2 + m) * 9;
    #pragma unroll
    for (int t = 0; t < 9; t++) up[t] = u[t];
}

// Shared staging: g0/g1 34x34 halo tiles (stride 35 to break bank conflicts)
__device__ __forceinline__ void stage_g(const float* __restrict__ cs, int b, int ty0, int tx0,
                                        const float* __restrict__ Wcval,
                                        const float* __restrict__ Wattn,
                                        const float* __restrict__ Wcomb,
                                        float* h0, float* h1) {
    float wa[8], wt[8];
    #pragma unroll
    for (int s = 0; s < 8; s++) { wa[s] = Wcomb[s] * Wcval[s]; wt[s] = Wattn[s]; }
    for (int idx = threadIdx.x; idx < 34 * 34; idx += 256) {
        int i = idx / 34, j = idx - (idx / 34) * 34;
        int gy = ty0 - 1 + i, gx = tx0 - 1 + j;
        float a0 = 0.f, a1 = 0.f;
        if ((unsigned)gy < HH && (unsigned)gx < WWD) {
            int p = gy * WWD + gx;
            float c0 = sigm(cs[(b * NC + 0) * P + p]);
            float c1 = sigm(cs[(b * NC + 1) * P + p]);
            #pragma unroll
            for (int s = 0; s < 8; s++) {
                a0 += wa[s] * sigm(c0 * wt[s]);
                a1 += wa[s] * sigm(c1 * wt[s]);
            }
        }
        h0[i * 35 + j] = a0; h1[i * 35 + j] = a1;
    }
}

// K5: compute y on the fly, per-block BN partials to unique slots (NO global atomics).
__launch_bounds__(256)
__global__ void k_cs(const float* __restrict__ cs, const float* __restrict__ U,
                     const float* __restrict__ Wcval, const float* __restrict__ Wattn,
                     const float* __restrict__ Wcomb, float* __restrict__ STp) {
    int tile = blockIdx.x, ocg = blockIdx.y, b = blockIdx.z;
    int ty0 = (tile / 6) * 32, tx0 = (tile % 6) * 32;
    __shared__ float h0[34 * 35], h1[34 * 35];
    stage_g(cs, b, ty0, tx0, Wcval, Wattn, Wcomb, h0, h1);
    __syncthreads();

    int w = __builtin_amdgcn_readfirstlane(threadIdx.x >> 6);
    int lane = threadIdx.x & 63;
    int oc0 = ocg * 8 + w * 2;
    float u0[2][9], u1[2][9];
    #pragma unroll
    for (int j = 0; j < 2; j++) {
        const float* up = U + ((b * C + oc0 + j) * 2) * 9;
        #pragma unroll
        for (int t = 0; t < 9; t++) { u0[j][t] = up[t]; u1[j][t] = up[9 + t]; }
    }
    float s1[2] = {0.f, 0.f}, s2[2] = {0.f, 0.f};
    for (int it = 0; it < 4; it++) {
        int row = it * 8 + (lane >> 3);
        int c0 = (lane & 7) * 4;
        float g0v[3][6], g1v[3][6];
        #pragma unroll
        for (int dy = 0; dy < 3; dy++)
            #pragma unroll
            for (int dx = 0; dx < 6; dx++) {
                g0v[dy][dx] = h0[(row + dy) * 35 + c0 + dx];
                g1v[dy][dx] = h1[(row + dy) * 35 + c0 + dx];
            }
        #pragma unroll
        for (int j = 0; j < 2; j++)
            #pragma unroll
            for (int px = 0; px < 4; px++) {
                float y = 0.f;
                #pragma unroll
                for (int ky = 0; ky < 3; ky++)
                    #pragma unroll
                    for (int kx = 0; kx < 3; kx++) {
                        y += u0[j][ky * 3 + kx] * g0v[ky][px + kx];
                        y += u1[j][ky * 3 + kx] * g1v[ky][px + kx];
                    }
                s1[j] += y; s2[j] += y * y;
            }
    }
    #pragma unroll
    for (int j = 0; j < 2; j++) {
        float a = s1[j], q = s2[j];
        for (int off = 32; off > 0; off >>= 1) { a += __shfl_down(a, off); q += __shfl_down(q, off); }
        if (lane == 0) {
            int slot = b * 36 + tile;
            STp[(oc0 + j) * 288 + slot] = a;
            STp[64 * 288 + (oc0 + j) * 288 + slot] = q;
        }
    }
}

// K6: finalize BN scale/shift from 288 per-block partials per channel (fp64 accumulate)
__global__ void k_bnfin(const float* __restrict__ STp, const float* __restrict__ gamma,
                        const float* __restrict__ beta, float* __restrict__ scale,
                        float* __restrict__ shift) {
    int oc = threadIdx.x;
    double s = 0.0, s2 = 0.0;
    for (int k = 0; k < 288; k++) {
        s  += (double)STp[oc * 288 + k];
        s2 += (double)STp[64 * 288 + oc * 288 + k];
    }
    double n = (double)(B * P);
    double mean = s / n;
    double var = s2 / n - mean * mean;
    float sc = gamma[oc] * rsqrtf((float)var + 1e-5f);
    scale[oc] = sc;
    shift[oc] = beta[oc] - (float)mean * sc;
}

// K7: recompute y, out = x + relu(y*scale+shift)
__launch_bounds__(256)
__global__ void k_fin2(const float* __restrict__ cs, const float* __restrict__ U,
                       const float* __restrict__ Wcval, const float* __restrict__ Wattn,
                       const float* __restrict__ Wcomb, const float* __restrict__ x,
                       const float* __restrict__ scale, const float* __restrict__ shift,
                       float* __restrict__ out) {
    int tile = blockIdx.x, ocg = blockIdx.y, b = blockIdx.z;
    int ty0 = (tile / 6) * 32, tx0 = (tile % 6) * 32;
    __shared__ float h0[34 * 35], h1[34 * 35];
    stage_g(cs, b, ty0, tx0, Wcval, Wattn, Wcomb, h0, h1);
    __syncthreads();

    int w = __builtin_amdgcn_readfirstlane(threadIdx.x >> 6);
    int lane = threadIdx.x & 63;
    int oc0 = ocg * 8 + w * 2;
    float u0[2][9], u1[2][9], sc[2], sh[2];
    #pragma unroll
    for (int j = 0; j < 2; j++) {
        const float* up = U + ((b * C + oc0 + j) * 2) * 9;
        #pragma unroll
        for (int t = 0; t < 9; t++) { u0[j][t] = up[t]; u1[j][t] = up[9 + t]; }
        sc[j] = scale[oc0 + j]; sh[j] = shift[oc0 + j];
    }
    for (int it = 0; it < 4; it++) {
        int row = it * 8 + (lane >> 3);
        int c0 = (lane & 7) * 4;
        float g0v[3][6], g1v[3][6];
        #pragma unroll
        for (int dy = 0; dy < 3; dy++)
            #pragma unroll
            for (int dx = 0; dx < 6; dx++) {
                g0v[dy][dx] = h0[(row + dy) * 35 + c0 + dx];
                g1v[dy][dx] = h1[(row + dy) * 35 + c0 + dx];
            }
        #pragma unroll
        for (int j = 0; j < 2; j++) {
            float y4[4];
            #pragma unroll
            for (int px = 0; px < 4; px++) {
                float y = 0.f;
                #pragma unroll
                for (int ky = 0; ky < 3; ky++)
                    #pragma unroll
                    for (int kx = 0; kx < 3; kx++) {
                        y += u0[j][ky * 3 + kx] * g0v[ky][px + kx];
                        y += u1[j][ky * 3 + kx] * g1v[ky][px + kx];
                    }
                y4[px] = y;
            }
            int ga = (b * C + oc0 + j) * P + (ty0 + row) * WWD + tx0 + c0;
            float4 xv = *(const float4*)(x + ga);
            float4 ov;
            ov.x = fmaxf(y4[0] * sc[j] + sh[j], 0.f) + xv.x;
            ov.y = fmaxf(y4[1] * sc[j] + sh[j], 0.f) + xv.y;
            ov.z = fmaxf(y4[2] * sc[j] + sh[j], 0.f) + xv.z;
            ov.w = fmaxf(y4[3] * sc[j] + sh[j], 0.f) + xv.w;
            *(float4*)(out + ga) = ov;
        }
    }
}

extern "C" void kernel_launch(void* const* d_in, const int* in_sizes, int n_in,
                              void* d_out, int out_size, void* d_ws, size_t ws_size,
                              hipStream_t stream) {
    const float* x     = (const float*)d_in[0];
    const float* cs    = (const float*)d_in[1];
    const float* Wc    = (const float*)d_in[2];
    const float* Wxs   = (const float*)d_in[3];
    const float* Wcsp  = (const float*)d_in[4];
    const float* Wcval = (const float*)d_in[5];
    const float* Wattn = (const float*)d_in[6];
    const float* Wcomb = (const float*)d_in[7];
    const float* Wsing = (const float*)d_in[8];
    const float* gamma = (const float*)d_in[9];
    const float* beta  = (const float*)d_in[10];
    float* ws  = (float*)d_ws;
    float* out = (float*)d_out;

    float* spp   = ws + OFF_SPACE;
    float* Spart = ws + OFF_SPART;
    float* R     = ws + OFF_R;
    float* tok2  = ws + OFF_TOK2;
    float* U     = ws + OFF_U;
    float* STp   = ws + OFF_STP;
    float* scale = ws + OFF_SCALE;
    float* shift = ws + OFF_SHIFT;

    // zero padded-space halos + R accumulator + tok2 accumulator (contiguous range)
    hipMemsetAsync(ws, 0, (size_t)(OFF_TOK2 + 1024) * sizeof(float), stream);

    k_space<<<dim3(144, 16), 256, 0, stream>>>(cs, Wc, spp, Spart);
    k_R2   <<<dim3(8, 64, 8), 256, 0, stream>>>(x, spp, R);
    k_tok2 <<<dim3(16, 8), 64, 0, stream>>>(Wxs, Wcsp, R, Spart, tok2);
    k_U    <<<dim3(8, 2), 64, 0, stream>>>(Wsing, tok2, U);
    k_cs   <<<dim3(36, 8, 8), 256, 0, stream>>>(cs, U, Wcval, Wattn, Wcomb, STp);
    k_bnfin<<<1, 64, 0, stream>>>(STp, gamma, beta, scale, shift);
    k_fin2 <<<dim3(36, 8, 8), 256, 0, stream>>>(cs, U, Wcval, Wattn, Wcomb, x, scale, shift, out);
}

// Round 4
// 472.924 us; speedup vs baseline: 1.0259x; 1.0259x over previous
//
#include <hip/hip_runtime.h>
#include <math.h>

// Problem constants (fixed by reference setup_inputs)
#define B   8
#define C   64
#define HH  192
#define WWD 192
#define P   (HH*WWD)     // 36864
#define NC  2
#define NS  8
#define PP  (194*194)    // padded space map (1-px zero halo), 37636

// Workspace layout (float offsets)
#define OFF_SPACE 0                    // 128 maps * PP = 4817408 (zero-padded)
#define OFF_SPART 4817408              // 128*144 per-block S partials
#define OFF_R     4835840              // 8*16*64*9 = 73728 correlations (zeroed; k_R2 atomically accumulates)
#define OFF_TOK2  4909568              // 8*2*64 = 1024 (atomic accumulated, needs zero)
#define OFF_U     4910592              // 8*64*2*9 = 9216 collapsed conv weights
#define OFF_STP   4919808              // 2*64*288 BN partial sums
#define OFF_SCALE 4956672              // 64
#define OFF_SHIFT 4956736              // 64
#define WS_FLOATS 4956800              // ~19.8 MB total

__device__ __forceinline__ float sigm(float x) { return 1.0f / (1.0f + expf(-x)); }

// K1: space maps (sigmoid + 1->7 ch 3x3 conv + sigmoid) into zero-padded layout,
// plus per-(map,ch) per-block partial sums (NO global atomics).
__global__ void k_space(const float* __restrict__ cs, const float* __restrict__ Wc,
                        float* __restrict__ spp, float* __restrict__ Spart) {
    int m = blockIdx.y;                       // m = b*2 + c
    int bx = blockIdx.x;
    int p = bx * 256 + threadIdx.x;           // 144*256 == P exactly
    int h = p / WWD, w = p - (p / WWD) * WWD;
    float cp[9];
    #pragma unroll
    for (int ky = 0; ky < 3; ky++)
        #pragma unroll
        for (int kx = 0; kx < 3; kx++) {
            int hh = h + ky - 1, ww = w + kx - 1;
            float v = 0.f;  // zero-pad AFTER sigmoid (conv pads class_prob with 0)
            if ((unsigned)hh < HH && (unsigned)ww < WWD)
                v = sigm(cs[m * P + hh * WWD + ww]);
            cp[ky * 3 + kx] = v;
        }
    float ch[8];
    ch[0] = cp[4];
    #pragma unroll
    for (int j = 0; j < 7; j++) {
        float a = 0.f;
        #pragma unroll
        for (int k = 0; k < 9; k++) a += Wc[j * 9 + k] * cp[k];
        ch[j + 1] = sigm(a);
    }
    #pragma unroll
    for (int q = 0; q < 8; q++)
        spp[(m * 8 + q) * PP + (h + 1) * 194 + (w + 1)] = ch[q];
    // per-wave shfl reduce -> LDS -> per-block partial (no atomics)
    __shared__ float red[4][8];
    int lane = threadIdx.x & 63, wave = threadIdx.x >> 6;
    #pragma unroll
    for (int q = 0; q < 8; q++) {
        float v = ch[q];
        for (int off = 32; off > 0; off >>= 1) v += __shfl_down(v, off);
        if (lane == 0) red[wave][q] = v;
    }
    __syncthreads();
    if (threadIdx.x < 8) {
        int q = threadIdx.x;
        Spart[(m * 8 + q) * 144 + bx] = red[0][q] + red[1][q] + red[2][q] + red[3][q];
    }
}

// K2: register-tiled correlation, one space map x 8 x-channels per block (84-reg core,
// the R1 config that measured 188us). NEW: XCD-chunked block swizzle.
// HW dispatch round-robins block ids across the 8 XCDs; we remap
//   logical = (bid%8)*256 + bid/8          (bijective, 2048 % 8 == 0)
// and decode logical with the space-map index sc in the LOW 4 bits, so the 16
// blocks sharing one x-slice (same b,ig,half, all 16 maps) are CONSECUTIVE on
// ONE XCD. Per-256-block chunk = one b: resident x slices (~1.8MB) + that b's
// whole g set (2.4MB) fit the 4MB per-XCD L2 -> re-reads served by L2, not L3.
// K-split x2 (half = bit 4); partials atomicAdd'd into R (pre-zeroed).
__launch_bounds__(256, 3)
__global__ void k_R2(const float* __restrict__ x, const float* __restrict__ spp,
                     float* __restrict__ R) {
    int bid = blockIdx.x;                       // 0..2047
    int logical = (bid & 7) * 256 + (bid >> 3); // XCD-chunked remap
    int sc   = logical & 15;                    // map index: innermost -> L2 sharing
    int half = (logical >> 4) & 1;              // K-split half
    int ig   = (logical >> 5) & 7;              // x channel-group
    int b    = logical >> 8;                    // batch: one per XCD chunk
    int s = sc >> 1, c = sc & 1;
    const float* xb = x + (b * C + ig * 8) * P;
    const float* sp = spp + ((b * NC + c) * NS + s) * PP;

    float acc[8][9];
    #pragma unroll
    for (int i = 0; i < 8; i++)
        #pragma unroll
        for (int t = 0; t < 9; t++) acc[i][t] = 0.f;

    for (int it = half * 18; it < half * 18 + 18; it++) {
        int p0 = it * 1024 + threadIdx.x * 4;
        int h = p0 / WWD, w0 = p0 - (p0 / WWD) * WWD;
        float4 xv[8];
        #pragma unroll
        for (int i = 0; i < 8; i++) xv[i] = *(const float4*)(xb + i * P + p0);
        float g[3][6];
        #pragma unroll
        for (int ty = 0; ty < 3; ty++) {
            const float* rp = sp + (h + 2 - ty) * 194 + w0;
            #pragma unroll
            for (int cc = 0; cc < 6; cc++) g[ty][cc] = rp[cc];
        }
        #pragma unroll
        for (int ty = 0; ty < 3; ty++)
            #pragma unroll
            for (int tx = 0; tx < 3; tx++) {
                float g0 = g[ty][2 - tx], g1 = g[ty][3 - tx];
                float g2 = g[ty][4 - tx], g3 = g[ty][5 - tx];
                #pragma unroll
                for (int i = 0; i < 8; i++) {
                    float a = acc[i][ty * 3 + tx];
                    a += xv[i].x * g0; a += xv[i].y * g1;
                    a += xv[i].z * g2; a += xv[i].w * g3;
                    acc[i][ty * 3 + tx] = a;
                }
            }
    }

    __shared__ float red[4][72];
    int lane = threadIdx.x & 63, wave = threadIdx.x >> 6;
    #pragma unroll
    for (int i = 0; i < 8; i++)
        #pragma unroll
        for (int t = 0; t < 9; t++) {
            float v = acc[i][t];
            for (int off = 32; off > 0; off >>= 1) v += __shfl_down(v, off);
            if (lane == 0) red[wave][i * 9 + t] = v;
        }
    __syncthreads();
    if (threadIdx.x < 72) {
        int i = threadIdx.x / 9, t = threadIdx.x - (threadIdx.x / 9) * 9;
        float v = red[0][threadIdx.x] + red[1][threadIdx.x] +
                  red[2][threadIdx.x] + red[3][threadIdx.x];
        atomicAdd(&R[((b * 16 + sc) * 64 + (ig * 8 + i)) * 9 + t], v);
    }
}

// K3: tok2[b,c,d] = sum_s Wcs[s]/S[b,c,s] * sum_{i,k} Wxs[s*64+d,i,k] * R[b,s,c,i,k]
// S reduced in-block from Spart (144 partials).
__global__ void k_tok2(const float* __restrict__ Wxs, const float* __restrict__ Wcs,
                       const float* __restrict__ R, const float* __restrict__ Spart,
                       float* __restrict__ tok2) {
    int bc = blockIdx.x, s = blockIdx.y;
    int d = threadIdx.x;
    const float* spp = Spart + (bc * 8 + s) * 144;
    float sv = 0.f;
    for (int k = d; k < 144; k += 64) sv += spp[k];
    #pragma unroll
    for (int msk = 32; msk >= 1; msk >>= 1) sv += __shfl_xor(sv, msk);

    const float* Rp = R + ((bc & 1) + ((bc >> 1) * 16 + s * 2)) * 64 * 9;
    const float* Wp = Wxs + (s * C + d) * (C * 9);
    float a = 0.f;
    for (int t = 0; t < C * 9; t++) a += Wp[t] * Rp[t];
    float val = a * Wcs[s] / sv;
    atomicAdd(&tok2[bc * C + d], val);   // 8K atomics over 1024 addrs — negligible
}

// K4: collapse conv weights against tok2:  U[b][oc][m][t] = sum_ci Ws[oc,ci,t] * tok2[b,m,ci]
__global__ void k_U(const float* __restrict__ Ws, const float* __restrict__ tok2,
                    float* __restrict__ U) {
    int b = blockIdx.x, m = blockIdx.y, oc = threadIdx.x;
    const float* tp = tok2 + (b * NC + m) * C;
    float u[9];
    #pragma unroll
    for (int t = 0; t < 9; t++) u[t] = 0.f;
    for (int ci = 0; ci < C; ci++) {
        float tv = tp[ci];
        const float* wp = Ws + (oc * C + ci) * 9;
        #pragma unroll
        for (int t = 0; t < 9; t++) u[t] += wp[t] * tv;
    }
    float* up = U + ((b * C + oc) * 2 + m) * 9;
    #pragma unroll
    for (int t = 0; t < 9; t++) up[t] = u[t];
}

// Shared staging: g0/g1 34x34 halo tiles (stride 35 to break bank conflicts)
__device__ __forceinline__ void stage_g(const float* __restrict__ cs, int b, int ty0, int tx0,
                                        const float* __restrict__ Wcval,
                                        const float* __restrict__ Wattn,
                                        const float* __restrict__ Wcomb,
                                        float* h0, float* h1) {
    float wa[8], wt[8];
    #pragma unroll
    for (int s = 0; s < 8; s++) { wa[s] = Wcomb[s] * Wcval[s]; wt[s] = Wattn[s]; }
    for (int idx = threadIdx.x; idx < 34 * 34; idx += 256) {
        int i = idx / 34, j = idx - (idx / 34) * 34;
        int gy = ty0 - 1 + i, gx = tx0 - 1 + j;
        float a0 = 0.f, a1 = 0.f;
        if ((unsigned)gy < HH && (unsigned)gx < WWD) {
            int p = gy * WWD + gx;
            float c0 = sigm(cs[(b * NC + 0) * P + p]);
            float c1 = sigm(cs[(b * NC + 1) * P + p]);
            #pragma unroll
            for (int s = 0; s < 8; s++) {
                a0 += wa[s] * sigm(c0 * wt[s]);
                a1 += wa[s] * sigm(c1 * wt[s]);
            }
        }
        h0[i * 35 + j] = a0; h1[i * 35 + j] = a1;
    }
}

// K5: compute y on the fly, per-block BN partials to unique slots (NO global atomics).
__launch_bounds__(256)
__global__ void k_cs(const float* __restrict__ cs, const float* __restrict__ U,
                     const float* __restrict__ Wcval, const float* __restrict__ Wattn,
                     const float* __restrict__ Wcomb, float* __restrict__ STp) {
    int tile = blockIdx.x, ocg = blockIdx.y, b = blockIdx.z;
    int ty0 = (tile / 6) * 32, tx0 = (tile % 6) * 32;
    __shared__ float h0[34 * 35], h1[34 * 35];
    stage_g(cs, b, ty0, tx0, Wcval, Wattn, Wcomb, h0, h1);
    __syncthreads();

    int w = __builtin_amdgcn_readfirstlane(threadIdx.x >> 6);
    int lane = threadIdx.x & 63;
    int oc0 = ocg * 8 + w * 2;
    float u0[2][9], u1[2][9];
    #pragma unroll
    for (int j = 0; j < 2; j++) {
        const float* up = U + ((b * C + oc0 + j) * 2) * 9;
        #pragma unroll
        for (int t = 0; t < 9; t++) { u0[j][t] = up[t]; u1[j][t] = up[9 + t]; }
    }
    float s1[2] = {0.f, 0.f}, s2[2] = {0.f, 0.f};
    for (int it = 0; it < 4; it++) {
        int row = it * 8 + (lane >> 3);
        int c0 = (lane & 7) * 4;
        float g0v[3][6], g1v[3][6];
        #pragma unroll
        for (int dy = 0; dy < 3; dy++)
            #pragma unroll
            for (int dx = 0; dx < 6; dx++) {
                g0v[dy][dx] = h0[(row + dy) * 35 + c0 + dx];
                g1v[dy][dx] = h1[(row + dy) * 35 + c0 + dx];
            }
        #pragma unroll
        for (int j = 0; j < 2; j++)
            #pragma unroll
            for (int px = 0; px < 4; px++) {
                float y = 0.f;
                #pragma unroll
                for (int ky = 0; ky < 3; ky++)
                    #pragma unroll
                    for (int kx = 0; kx < 3; kx++) {
                        y += u0[j][ky * 3 + kx] * g0v[ky][px + kx];
                        y += u1[j][ky * 3 + kx] * g1v[ky][px + kx];
                    }
                s1[j] += y; s2[j] += y * y;
            }
    }
    #pragma unroll
    for (int j = 0; j < 2; j++) {
        float a = s1[j], q = s2[j];
        for (int off = 32; off > 0; off >>= 1) { a += __shfl_down(a, off); q += __shfl_down(q, off); }
        if (lane == 0) {
            int slot = b * 36 + tile;
            STp[(oc0 + j) * 288 + slot] = a;
            STp[64 * 288 + (oc0 + j) * 288 + slot] = q;
        }
    }
}

// K6: finalize BN scale/shift from 288 per-block partials per channel (fp64 accumulate)
__global__ void k_bnfin(const float* __restrict__ STp, const float* __restrict__ gamma,
                        const float* __restrict__ beta, float* __restrict__ scale,
                        float* __restrict__ shift) {
    int oc = threadIdx.x;
    double s = 0.0, s2 = 0.0;
    for (int k = 0; k < 288; k++) {
        s  += (double)STp[oc * 288 + k];
        s2 += (double)STp[64 * 288 + oc * 288 + k];
    }
    double n = (double)(B * P);
    double mean = s / n;
    double var = s2 / n - mean * mean;
    float sc = gamma[oc] * rsqrtf((float)var + 1e-5f);
    scale[oc] = sc;
    shift[oc] = beta[oc] - (float)mean * sc;
}

// K7: recompute y, out = x + relu(y*scale+shift)
__launch_bounds__(256)
__global__ void k_fin2(const float* __restrict__ cs, const float* __restrict__ U,
                       const float* __restrict__ Wcval, const float* __restrict__ Wattn,
                       const float* __restrict__ Wcomb, const float* __restrict__ x,
                       const float* __restrict__ scale, const float* __restrict__ shift,
                       float* __restrict__ out) {
    int tile = blockIdx.x, ocg = blockIdx.y, b = blockIdx.z;
    int ty0 = (tile / 6) * 32, tx0 = (tile % 6) * 32;
    __shared__ float h0[34 * 35], h1[34 * 35];
    stage_g(cs, b, ty0, tx0, Wcval, Wattn, Wcomb, h0, h1);
    __syncthreads();

    int w = __builtin_amdgcn_readfirstlane(threadIdx.x >> 6);
    int lane = threadIdx.x & 63;
    int oc0 = ocg * 8 + w * 2;
    float u0[2][9], u1[2][9], sc[2], sh[2];
    #pragma unroll
    for (int j = 0; j < 2; j++) {
        const float* up = U + ((b * C + oc0 + j) * 2) * 9;
        #pragma unroll
        for (int t = 0; t < 9; t++) { u0[j][t] = up[t]; u1[j][t] = up[9 + t]; }
        sc[j] = scale[oc0 + j]; sh[j] = shift[oc0 + j];
    }
    for (int it = 0; it < 4; it++) {
        int row = it * 8 + (lane >> 3);
        int c0 = (lane & 7) * 4;
        float g0v[3][6], g1v[3][6];
        #pragma unroll
        for (int dy = 0; dy < 3; dy++)
            #pragma unroll
            for (int dx = 0; dx < 6; dx++) {
                g0v[dy][dx] = h0[(row + dy) * 35 + c0 + dx];
                g1v[dy][dx] = h1[(row + dy) * 35 + c0 + dx];
            }
        #pragma unroll
        for (int j = 0; j < 2; j++) {
            float y4[4];
            #pragma unroll
            for (int px = 0; px < 4; px++) {
                float y = 0.f;
                #pragma unroll
                for (int ky = 0; ky < 3; ky++)
                    #pragma unroll
                    for (int kx = 0; kx < 3; kx++) {
                        y += u0[j][ky * 3 + kx] * g0v[ky][px + kx];
                        y += u1[j][ky * 3 + kx] * g1v[ky][px + kx];
                    }
                y4[px] = y;
            }
            int ga = (b * C + oc0 + j) * P + (ty0 + row) * WWD + tx0 + c0;
            float4 xv = *(const float4*)(x + ga);
            float4 ov;
            ov.x = fmaxf(y4[0] * sc[j] + sh[j], 0.f) + xv.x;
            ov.y = fmaxf(y4[1] * sc[j] + sh[j], 0.f) + xv.y;
            ov.z = fmaxf(y4[2] * sc[j] + sh[j], 0.f) + xv.z;
            ov.w = fmaxf(y4[3] * sc[j] + sh[j], 0.f) + xv.w;
            *(float4*)(out + ga) = ov;
        }
    }
}

extern "C" void kernel_launch(void* const* d_in, const int* in_sizes, int n_in,
                              void* d_out, int out_size, void* d_ws, size_t ws_size,
                              hipStream_t stream) {
    const float* x     = (const float*)d_in[0];
    const float* cs    = (const float*)d_in[1];
    const float* Wc    = (const float*)d_in[2];
    const float* Wxs   = (const float*)d_in[3];
    const float* Wcsp  = (const float*)d_in[4];
    const float* Wcval = (const float*)d_in[5];
    const float* Wattn = (const float*)d_in[6];
    const float* Wcomb = (const float*)d_in[7];
    const float* Wsing = (const float*)d_in[8];
    const float* gamma = (const float*)d_in[9];
    const float* beta  = (const float*)d_in[10];
    float* ws  = (float*)d_ws;
    float* out = (float*)d_out;

    float* spp   = ws + OFF_SPACE;
    float* Spart = ws + OFF_SPART;
    float* R     = ws + OFF_R;
    float* tok2  = ws + OFF_TOK2;
    float* U     = ws + OFF_U;
    float* STp   = ws + OFF_STP;
    float* scale = ws + OFF_SCALE;
    float* shift = ws + OFF_SHIFT;

    // zero padded-space halos + R accumulator + tok2 accumulator (contiguous range)
    hipMemsetAsync(ws, 0, (size_t)(OFF_TOK2 + 1024) * sizeof(float), stream);

    k_space<<<dim3(144, 16), 256, 0, stream>>>(cs, Wc, spp, Spart);
    k_R2   <<<dim3(2048), 256, 0, stream>>>(x, spp, R);
    k_tok2 <<<dim3(16, 8), 64, 0, stream>>>(Wxs, Wcsp, R, Spart, tok2);
    k_U    <<<dim3(8, 2), 64, 0, stream>>>(Wsing, tok2, U);
    k_cs   <<<dim3(36, 8, 8), 256, 0, stream>>>(cs, U, Wcval, Wattn, Wcomb, STp);
    k_bnfin<<<1, 64, 0, stream>>>(STp, gamma, beta, scale, shift);
    k_fin2 <<<dim3(36, 8, 8), 256, 0, stream>>>(cs, U, Wcval, Wattn, Wcomb, x, scale, shift, out);
}

// Round 5
// 426.616 us; speedup vs baseline: 1.1373x; 1.1085x over previous
//
#include <hip/hip_runtime.h>
#include <math.h>

// Problem constants (fixed by reference setup_inputs)
#define B   8
#define C   64
#define HH  192
#define WWD 192
#define P   (HH*WWD)     // 36864
#define NC  2
#define NS  8
#define PP  (194*194)    // padded space map (1-px zero halo), 37636

// Workspace layout (float offsets)
#define OFF_SPACE 0                    // 128 maps * PP = 4817408 (zero-padded)
// Wt and gmap REUSE the spp region (dead after k_R2): k_wt/k_g run after k_R2.
#define OFF_WT    0                    // 8*576*64 = 294912 transposed Wxs
#define OFF_GM    294912               // 8*2*P = 589824 combined attention maps
#define OFF_SPART 4817408              // 128*144 per-block S partials
#define OFF_R     4835840              // 8*16*64*9 = 73728 correlations (zeroed; k_R2 atomically accumulates)
#define OFF_TOK2  4909568              // 8*2*64 = 1024 (atomic accumulated, needs zero)
#define OFF_U     4910592              // 8*64*2*9 = 9216 collapsed conv weights
#define OFF_STP   4919808              // 2*64*288 BN partial sums ([slot][oc] major now)
#define OFF_SCALE 4956672              // 64
#define OFF_SHIFT 4956736              // 64
#define WS_FLOATS 4956800              // ~19.8 MB total

__device__ __forceinline__ float sigm(float x) { return 1.0f / (1.0f + expf(-x)); }

// K1: space maps (sigmoid + 1->7 ch 3x3 conv + sigmoid) into zero-padded layout,
// plus per-(map,ch) per-block partial sums (NO global atomics).
__global__ void k_space(const float* __restrict__ cs, const float* __restrict__ Wc,
                        float* __restrict__ spp, float* __restrict__ Spart) {
    int m = blockIdx.y;                       // m = b*2 + c
    int bx = blockIdx.x;
    int p = bx * 256 + threadIdx.x;           // 144*256 == P exactly
    int h = p / WWD, w = p - (p / WWD) * WWD;
    float cp[9];
    #pragma unroll
    for (int ky = 0; ky < 3; ky++)
        #pragma unroll
        for (int kx = 0; kx < 3; kx++) {
            int hh = h + ky - 1, ww = w + kx - 1;
            float v = 0.f;  // zero-pad AFTER sigmoid (conv pads class_prob with 0)
            if ((unsigned)hh < HH && (unsigned)ww < WWD)
                v = sigm(cs[m * P + hh * WWD + ww]);
            cp[ky * 3 + kx] = v;
        }
    float ch[8];
    ch[0] = cp[4];
    #pragma unroll
    for (int j = 0; j < 7; j++) {
        float a = 0.f;
        #pragma unroll
        for (int k = 0; k < 9; k++) a += Wc[j * 9 + k] * cp[k];
        ch[j + 1] = sigm(a);
    }
    #pragma unroll
    for (int q = 0; q < 8; q++)
        spp[(m * 8 + q) * PP + (h + 1) * 194 + (w + 1)] = ch[q];
    // per-wave shfl reduce -> LDS -> per-block partial (no atomics)
    __shared__ float red[4][8];
    int lane = threadIdx.x & 63, wave = threadIdx.x >> 6;
    #pragma unroll
    for (int q = 0; q < 8; q++) {
        float v = ch[q];
        for (int off = 32; off > 0; off >>= 1) v += __shfl_down(v, off);
        if (lane == 0) red[wave][q] = v;
    }
    __syncthreads();
    if (threadIdx.x < 8) {
        int q = threadIdx.x;
        Spart[(m * 8 + q) * 144 + bx] = red[0][q] + red[1][q] + red[2][q] + red[3][q];
    }
}

// K2: register-tiled correlation, one space map x 8 x-channels per block.
// R1 config (best measured: 188us): grid (8, 32, 8), K-split x2, no swizzle.
// NEW vs R1: g row loads vectorized (dwordx4+dwordx2 via memcpy, unaligned-safe)
// -> 6 VMEM insts/iter for g instead of 18, ~36 fewer addr-calc VALU ops.
__launch_bounds__(256, 3)
__global__ void k_R2(const float* __restrict__ x, const float* __restrict__ spp,
                     float* __restrict__ R) {
    int ig = blockIdx.x;    // 0..7 : i = ig*8 + il
    int scz = blockIdx.y;   // 0..31 : sc = scz & 15, half = scz >> 4
    int b  = blockIdx.z;
    int sc = scz & 15;
    int half = scz >> 4;
    int s = sc >> 1, c = sc & 1;
    const float* xb = x + (b * C + ig * 8) * P;
    const float* sp = spp + ((b * NC + c) * NS + s) * PP;

    float acc[8][9];
    #pragma unroll
    for (int i = 0; i < 8; i++)
        #pragma unroll
        for (int t = 0; t < 9; t++) acc[i][t] = 0.f;

    for (int it = half * 18; it < half * 18 + 18; it++) {
        int p0 = it * 1024 + threadIdx.x * 4;
        int h = p0 / WWD, w0 = p0 - (p0 / WWD) * WWD;
        float4 xv[8];
        #pragma unroll
        for (int i = 0; i < 8; i++) xv[i] = *(const float4*)(xb + i * P + p0);
        float g[3][6];
        #pragma unroll
        for (int ty = 0; ty < 3; ty++) {
            const float* rp = sp + (h + 2 - ty) * 194 + w0;
            float4 ga; float2 gb;                 // rp is 4B-aligned; gfx950 allows
            __builtin_memcpy(&ga, rp, 16);        // unaligned dwordx4/dwordx2
            __builtin_memcpy(&gb, rp + 4, 8);
            g[ty][0] = ga.x; g[ty][1] = ga.y; g[ty][2] = ga.z;
            g[ty][3] = ga.w; g[ty][4] = gb.x; g[ty][5] = gb.y;
        }
        #pragma unroll
        for (int ty = 0; ty < 3; ty++)
            #pragma unroll
            for (int tx = 0; tx < 3; tx++) {
                float g0 = g[ty][2 - tx], g1 = g[ty][3 - tx];
                float g2 = g[ty][4 - tx], g3 = g[ty][5 - tx];
                #pragma unroll
                for (int i = 0; i < 8; i++) {
                    float a = acc[i][ty * 3 + tx];
                    a += xv[i].x * g0; a += xv[i].y * g1;
                    a += xv[i].z * g2; a += xv[i].w * g3;
                    acc[i][ty * 3 + tx] = a;
                }
            }
    }

    __shared__ float red[4][72];
    int lane = threadIdx.x & 63, wave = threadIdx.x >> 6;
    #pragma unroll
    for (int i = 0; i < 8; i++)
        #pragma unroll
        for (int t = 0; t < 9; t++) {
            float v = acc[i][t];
            for (int off = 32; off > 0; off >>= 1) v += __shfl_down(v, off);
            if (lane == 0) red[wave][i * 9 + t] = v;
        }
    __syncthreads();
    if (threadIdx.x < 72) {
        int i = threadIdx.x / 9, t = threadIdx.x - (threadIdx.x / 9) * 9;
        float v = red[0][threadIdx.x] + red[1][threadIdx.x] +
                  red[2][threadIdx.x] + red[3][threadIdx.x];
        atomicAdd(&R[((b * 16 + sc) * 64 + (ig * 8 + i)) * 9 + t], v);
    }
}

// K2b: transpose Wxs into Wt[s][t][d] so k_tok2's weight reads are lane-coalesced.
// Runs AFTER k_R2 (Wt lives in the dead spp region). 1.2 MB, trivial.
__global__ void k_wt(const float* __restrict__ Wxs, float* __restrict__ Wt) {
    int t = blockIdx.x;   // 0..575
    int s = blockIdx.y;   // 0..7
    int d = threadIdx.x;  // 0..63
    Wt[(s * 576 + t) * 64 + d] = Wxs[(s * 64 + d) * 576 + t];
}

// K2c: combined attention map gmap[b][cl][p] = sum_s Wcomb[s]*Wcval[s]*sigm(sigm(cs)*Wattn[s])
// Computed ONCE per pixel (was recomputed 8x per ocg in k_cs AND k_fin2).
__global__ void k_g(const float* __restrict__ cs, const float* __restrict__ Wcval,
                    const float* __restrict__ Wattn, const float* __restrict__ Wcomb,
                    float* __restrict__ gmap) {
    int m = blockIdx.y;                       // b*2 + cl
    int p = blockIdx.x * 256 + threadIdx.x;   // 144*256 == P
    float wa[8], wt[8];
    #pragma unroll
    for (int s = 0; s < 8; s++) { wa[s] = Wcomb[s] * Wcval[s]; wt[s] = Wattn[s]; }
    float cp = sigm(cs[m * P + p]);
    float a = 0.f;
    #pragma unroll
    for (int s = 0; s < 8; s++) a += wa[s] * sigm(cp * wt[s]);
    gmap[m * P + p] = a;
}

// K3: tok2[b,c,d] = sum_s Wcs[s]/S[b,c,s] * sum_{t} Wt[s][t][d] * R[b,s,c,t]
// Wt transposed -> coalesced weight loads; R row is a broadcast (L1-served).
__global__ void k_tok2(const float* __restrict__ Wt, const float* __restrict__ Wcs,
                       const float* __restrict__ R, const float* __restrict__ Spart,
                       float* __restrict__ tok2) {
    int bc = blockIdx.x, s = blockIdx.y;
    int d = threadIdx.x;
    const float* spp = Spart + (bc * 8 + s) * 144;
    float sv = 0.f;
    for (int k = d; k < 144; k += 64) sv += spp[k];
    #pragma unroll
    for (int msk = 32; msk >= 1; msk >>= 1) sv += __shfl_xor(sv, msk);

    const float* Rp = R + ((bc & 1) + ((bc >> 1) * 16 + s * 2)) * 576;
    const float* Wp = Wt + s * 576 * 64 + d;
    float a = 0.f;
    #pragma unroll 4
    for (int t = 0; t < 576; t++) a += Wp[t * 64] * Rp[t];
    float val = a * Wcs[s] / sv;
    atomicAdd(&tok2[bc * C + d], val);   // 8K atomics over 1024 addrs — negligible
}

// K4: collapse conv weights against tok2:  U[b][oc][m][t] = sum_ci Ws[oc,ci,t] * tok2[b,m,ci]
__global__ void k_U(const float* __restrict__ Ws, const float* __restrict__ tok2,
                    float* __restrict__ U) {
    int b = blockIdx.x, m = blockIdx.y, oc = threadIdx.x;
    const float* tp = tok2 + (b * NC + m) * C;
    float u[9];
    #pragma unroll
    for (int t = 0; t < 9; t++) u[t] = 0.f;
    for (int ci = 0; ci < C; ci++) {
        float tv = tp[ci];
        const float* wp = Ws + (oc * C + ci) * 9;
        #pragma unroll
        for (int t = 0; t < 9; t++) u[t] += wp[t] * tv;
    }
    float* up = U + ((b * C + oc) * 2 + m) * 9;
    #pragma unroll
    for (int t = 0; t < 9; t++) up[t] = u[t];
}

// Shared staging: g0/g1 34x34 halo tiles from precomputed gmap (pure coalesced copy).
__device__ __forceinline__ void stage_g(const float* __restrict__ gmap, int b, int ty0, int tx0,
                                        float* h0, float* h1) {
    const float* g0p = gmap + (b * NC + 0) * P;
    const float* g1p = gmap + (b * NC + 1) * P;
    for (int idx = threadIdx.x; idx < 34 * 34; idx += 256) {
        int i = idx / 34, j = idx - (idx / 34) * 34;
        int gy = ty0 - 1 + i, gx = tx0 - 1 + j;
        float a0 = 0.f, a1 = 0.f;
        if ((unsigned)gy < HH && (unsigned)gx < WWD) {
            int p = gy * WWD + gx;
            a0 = g0p[p]; a1 = g1p[p];
        }
        h0[i * 35 + j] = a0; h1[i * 35 + j] = a1;
    }
}

// K5: compute y on the fly, per-block BN partials to unique slots (NO global atomics).
// STp now [slot][oc]-major so k_bnfin reads coalesce.
__launch_bounds__(256)
__global__ void k_cs(const float* __restrict__ gmap, const float* __restrict__ U,
                     float* __restrict__ STp) {
    int tile = blockIdx.x, ocg = blockIdx.y, b = blockIdx.z;
    int ty0 = (tile / 6) * 32, tx0 = (tile % 6) * 32;
    __shared__ float h0[34 * 35], h1[34 * 35];
    stage_g(gmap, b, ty0, tx0, h0, h1);
    __syncthreads();

    int w = __builtin_amdgcn_readfirstlane(threadIdx.x >> 6);
    int lane = threadIdx.x & 63;
    int oc0 = ocg * 8 + w * 2;
    float u0[2][9], u1[2][9];
    #pragma unroll
    for (int j = 0; j < 2; j++) {
        const float* up = U + ((b * C + oc0 + j) * 2) * 9;
        #pragma unroll
        for (int t = 0; t < 9; t++) { u0[j][t] = up[t]; u1[j][t] = up[9 + t]; }
    }
    float s1[2] = {0.f, 0.f}, s2[2] = {0.f, 0.f};
    for (int it = 0; it < 4; it++) {
        int row = it * 8 + (lane >> 3);
        int c0 = (lane & 7) * 4;
        float g0v[3][6], g1v[3][6];
        #pragma unroll
        for (int dy = 0; dy < 3; dy++)
            #pragma unroll
            for (int dx = 0; dx < 6; dx++) {
                g0v[dy][dx] = h0[(row + dy) * 35 + c0 + dx];
                g1v[dy][dx] = h1[(row + dy) * 35 + c0 + dx];
            }
        #pragma unroll
        for (int j = 0; j < 2; j++)
            #pragma unroll
            for (int px = 0; px < 4; px++) {
                float y = 0.f;
                #pragma unroll
                for (int ky = 0; ky < 3; ky++)
                    #pragma unroll
                    for (int kx = 0; kx < 3; kx++) {
                        y += u0[j][ky * 3 + kx] * g0v[ky][px + kx];
                        y += u1[j][ky * 3 + kx] * g1v[ky][px + kx];
                    }
                s1[j] += y; s2[j] += y * y;
            }
    }
    #pragma unroll
    for (int j = 0; j < 2; j++) {
        float a = s1[j], q = s2[j];
        for (int off = 32; off > 0; off >>= 1) { a += __shfl_down(a, off); q += __shfl_down(q, off); }
        if (lane == 0) {
            int slot = b * 36 + tile;
            STp[slot * 64 + (oc0 + j)] = a;
            STp[288 * 64 + slot * 64 + (oc0 + j)] = q;
        }
    }
}

// K6: finalize BN scale/shift; STp [slot][oc]-major -> coalesced reads (fp64 accumulate)
__global__ void k_bnfin(const float* __restrict__ STp, const float* __restrict__ gamma,
                        const float* __restrict__ beta, float* __restrict__ scale,
                        float* __restrict__ shift) {
    int oc = threadIdx.x;
    double s = 0.0, s2 = 0.0;
    for (int k = 0; k < 288; k++) {
        s  += (double)STp[k * 64 + oc];
        s2 += (double)STp[288 * 64 + k * 64 + oc];
    }
    double n = (double)(B * P);
    double mean = s / n;
    double var = s2 / n - mean * mean;
    float sc = gamma[oc] * rsqrtf((float)var + 1e-5f);
    scale[oc] = sc;
    shift[oc] = beta[oc] - (float)mean * sc;
}

// K7: recompute y, out = x + relu(y*scale+shift)
__launch_bounds__(256)
__global__ void k_fin2(const float* __restrict__ gmap, const float* __restrict__ U,
                       const float* __restrict__ x,
                       const float* __restrict__ scale, const float* __restrict__ shift,
                       float* __restrict__ out) {
    int tile = blockIdx.x, ocg = blockIdx.y, b = blockIdx.z;
    int ty0 = (tile / 6) * 32, tx0 = (tile % 6) * 32;
    __shared__ float h0[34 * 35], h1[34 * 35];
    stage_g(gmap, b, ty0, tx0, h0, h1);
    __syncthreads();

    int w = __builtin_amdgcn_readfirstlane(threadIdx.x >> 6);
    int lane = threadIdx.x & 63;
    int oc0 = ocg * 8 + w * 2;
    float u0[2][9], u1[2][9], sc[2], sh[2];
    #pragma unroll
    for (int j = 0; j < 2; j++) {
        const float* up = U + ((b * C + oc0 + j) * 2) * 9;
        #pragma unroll
        for (int t = 0; t < 9; t++) { u0[j][t] = up[t]; u1[j][t] = up[9 + t]; }
        sc[j] = scale[oc0 + j]; sh[j] = shift[oc0 + j];
    }
    for (int it = 0; it < 4; it++) {
        int row = it * 8 + (lane >> 3);
        int c0 = (lane & 7) * 4;
        float g0v[3][6], g1v[3][6];
        #pragma unroll
        for (int dy = 0; dy < 3; dy++)
            #pragma unroll
            for (int dx = 0; dx < 6; dx++) {
                g0v[dy][dx] = h0[(row + dy) * 35 + c0 + dx];
                g1v[dy][dx] = h1[(row + dy) * 35 + c0 + dx];
            }
        #pragma unroll
        for (int j = 0; j < 2; j++) {
            float y4[4];
            #pragma unroll
            for (int px = 0; px < 4; px++) {
                float y = 0.f;
                #pragma unroll
                for (int ky = 0; ky < 3; ky++)
                    #pragma unroll
                    for (int kx = 0; kx < 3; kx++) {
                        y += u0[j][ky * 3 + kx] * g0v[ky][px + kx];
                        y += u1[j][ky * 3 + kx] * g1v[ky][px + kx];
                    }
                y4[px] = y;
            }
            int ga = (b * C + oc0 + j) * P + (ty0 + row) * WWD + tx0 + c0;
            float4 xv = *(const float4*)(x + ga);
            float4 ov;
            ov.x = fmaxf(y4[0] * sc[j] + sh[j], 0.f) + xv.x;
            ov.y = fmaxf(y4[1] * sc[j] + sh[j], 0.f) + xv.y;
            ov.z = fmaxf(y4[2] * sc[j] + sh[j], 0.f) + xv.z;
            ov.w = fmaxf(y4[3] * sc[j] + sh[j], 0.f) + xv.w;
            *(float4*)(out + ga) = ov;
        }
    }
}

extern "C" void kernel_launch(void* const* d_in, const int* in_sizes, int n_in,
                              void* d_out, int out_size, void* d_ws, size_t ws_size,
                              hipStream_t stream) {
    const float* x     = (const float*)d_in[0];
    const float* cs    = (const float*)d_in[1];
    const float* Wc    = (const float*)d_in[2];
    const float* Wxs   = (const float*)d_in[3];
    const float* Wcsp  = (const float*)d_in[4];
    const float* Wcval = (const float*)d_in[5];
    const float* Wattn = (const float*)d_in[6];
    const float* Wcomb = (const float*)d_in[7];
    const float* Wsing = (const float*)d_in[8];
    const float* gamma = (const float*)d_in[9];
    const float* beta  = (const float*)d_in[10];
    float* ws  = (float*)d_ws;
    float* out = (float*)d_out;

    float* spp   = ws + OFF_SPACE;
    float* Wt    = ws + OFF_WT;      // overlays spp (dead after k_R2)
    float* gmap  = ws + OFF_GM;      // overlays spp (dead after k_R2)
    float* Spart = ws + OFF_SPART;
    float* R     = ws + OFF_R;
    float* tok2  = ws + OFF_TOK2;
    float* U     = ws + OFF_U;
    float* STp   = ws + OFF_STP;
    float* scale = ws + OFF_SCALE;
    float* shift = ws + OFF_SHIFT;

    // zero padded-space halos + R accumulator + tok2 accumulator (contiguous range)
    hipMemsetAsync(ws, 0, (size_t)(OFF_TOK2 + 1024) * sizeof(float), stream);

    k_space<<<dim3(144, 16), 256, 0, stream>>>(cs, Wc, spp, Spart);
    k_R2   <<<dim3(8, 32, 8), 256, 0, stream>>>(x, spp, R);
    k_wt   <<<dim3(576, 8), 64, 0, stream>>>(Wxs, Wt);           // spp dead from here
    k_g    <<<dim3(144, 16), 256, 0, stream>>>(cs, Wcval, Wattn, Wcomb, gmap);
    k_tok2 <<<dim3(16, 8), 64, 0, stream>>>(Wt, Wcsp, R, Spart, tok2);
    k_U    <<<dim3(8, 2), 64, 0, stream>>>(Wsing, tok2, U);
    k_cs   <<<dim3(36, 8, 8), 256, 0, stream>>>(gmap, U, STp);
    k_bnfin<<<1, 64, 0, stream>>>(STp, gamma, beta, scale, shift);
    k_fin2 <<<dim3(36, 8, 8), 256, 0, stream>>>(gmap, U, x, scale, shift, out);
}